// Round 9
// baseline (256.058 us; speedup 1.0000x reference)
//
#include <hip/hip_runtime.h>
#include <math.h>

#define NN 50000
#define NE 600000
#define NP 200000
#define NB_SCAN 49  // ceil(NN / 1024)

typedef unsigned int uint;
typedef unsigned short ushort;
typedef __attribute__((ext_vector_type(8))) short bf16x8;
typedef __attribute__((ext_vector_type(4))) float f32x4;

// ---- bf16 helpers (RNE) ----
__device__ __forceinline__ ushort f2bf(float f) {
    uint u = __float_as_uint(f);
    uint r = (u + 0x7FFFu + ((u >> 16) & 1u)) >> 16;
    return (ushort)r;
}
__device__ __forceinline__ float bf2f(uint lo16) {
    return __uint_as_float(lo16 << 16);
}

__device__ __forceinline__ int wave_iscan(int v, int lane) {
#pragma unroll
    for (int off = 1; off < 64; off <<= 1) {
        int t = __shfl_up(v, off, 64);
        if (lane >= off) v += t;
    }
    return v;
}

// ---- W swizzle into MFMA B-operand layout (bf16) ----
// Bp[((ct*(N/16)+nt)*64 + lane)*8 + j] = Wcat[ct*32 + (lane>>4)*8 + j][nt*16 + (lane&15)]
template <int K, int N>
__device__ __forceinline__ void prepB_one(int idx, const float* __restrict__ Wt,
                                          const float* __restrict__ Wb,
                                          ushort* __restrict__ Bp) {
    int lane = idx & 63;
    int nt = (idx >> 6) % (N / 16);
    int ct = idx / (64 * (N / 16));
    int n = nt * 16 + (lane & 15);
    int kb = ct * 32 + (lane >> 4) * 8;
#pragma unroll
    for (int j = 0; j < 8; j++) {
        int k = kb + j;
        float w = (k < K / 2) ? Wt[(size_t)k * N + n] : Wb[(size_t)(k - K / 2) * N + n];
        Bp[(size_t)idx * 8 + j] = f2bf(w);
    }
}

// ---------------- fused prologue ----------------
// ranges: x->bf16 (float4) | deg histogram | Bp1 swizzle | pq vectors | cab scalars
// pq[0:256]=W2l@wa, pq[256:512]=W2l@wb, pq[512:768]=W2r@wa, pq[768:1024]=W2r@wb
#define T_PREP (NN * 32)
#define T_DEG  (T_PREP + NE)
#define T_B1   (T_DEG + 8192)
#define T_PQ   (T_B1 + 1024)
#define T_CAB  (T_PQ + 2)
__global__ void k_pre(const float* __restrict__ x, uint* __restrict__ xbf,
                      const int* __restrict__ dst, int* __restrict__ deg,
                      const float* __restrict__ W1l, const float* __restrict__ W1r,
                      ushort* __restrict__ Bp1,
                      const float* __restrict__ W2l, const float* __restrict__ W2r,
                      const float* __restrict__ Wlin, const float* __restrict__ b2l,
                      float* __restrict__ pq, float* __restrict__ cab) {
    int t = blockIdx.x * 256 + threadIdx.x;
    if (t < T_PREP) {
        int n = t >> 5, c4 = t & 31;
        float4 v = *(const float4*)(x + (size_t)n * 128 + c4 * 4);
        uint2 o;
        o.x = (uint)f2bf(v.x) | ((uint)f2bf(v.y) << 16);
        o.y = (uint)f2bf(v.z) | ((uint)f2bf(v.w) << 16);
        *(uint2*)(xbf + (size_t)n * 64 + c4 * 2) = o;
    } else if (t < T_DEG) {
        atomicAdd(deg + dst[t - T_PREP], 1);
    } else if (t < T_B1) {
        prepB_one<256, 256>(t - T_DEG, W1l, W1r, Bp1);
    } else if (t < T_PQ) {
        int idx = t - T_B1;
        int vec = idx >> 8;          // 0..3
        int k = idx & 255;
        const float* W = (vec < 2) ? W2l : W2r;    // [256,128]
        const float* wl = Wlin + (vec & 1) * 128;  // wa or wb
        float s = 0.f;
#pragma unroll 4
        for (int j = 0; j < 128; j++) s += W[(size_t)k * 128 + j] * wl[j];
        pq[idx] = s;
    } else if (t < T_CAB) {
        int i = t - T_PQ;
        float s = 0.f;
        for (int j = 0; j < 128; j++) s += b2l[j] * Wlin[i * 128 + j];
        cab[i] = s;
    }
}

// ---------------- scan phase 1: per-block exclusive values + block sums ----------------
__global__ __launch_bounds__(1024) void k_scan1(const int* __restrict__ deg,
                                                int* __restrict__ excl,
                                                int* __restrict__ bsum) {
    int tid = threadIdx.x;
    int i = blockIdx.x * 1024 + tid;
    int lane = tid & 63, wid = tid >> 6;
    int v = (i < NN) ? deg[i] : 0;
    int incl = wave_iscan(v, lane);
    __shared__ int wt[16];
    if (lane == 63) wt[wid] = incl;
    __syncthreads();
    if (tid < 16) {
        int w = wt[tid];
#pragma unroll
        for (int off = 1; off < 16; off <<= 1) {
            int t = __shfl_up(w, off, 64);
            if (tid >= off) w += t;
        }
        wt[tid] = w;
    }
    __syncthreads();
    int base = (wid > 0) ? wt[wid - 1] : 0;
    if (i < NN) excl[i] = incl - v + base;
    if (tid == 0) bsum[blockIdx.x] = wt[15];
}

// ---------------- scan phases 2+3 merged: each block rescans bsum (49 ints, free) ------
__global__ __launch_bounds__(1024) void k_scan23(const int* __restrict__ excl,
                                                 const int* __restrict__ bsum,
                                                 int* __restrict__ rowptr,
                                                 int* __restrict__ cursor) {
    __shared__ int boff;
    int tid = threadIdx.x;
    if (tid < 64) {
        int v = (tid < NB_SCAN) ? bsum[tid] : 0;
        int incl = wave_iscan(v, tid);
        if (tid == (int)blockIdx.x) boff = incl - v;  // exclusive prefix at this block
    }
    __syncthreads();
    int i = blockIdx.x * 1024 + tid;
    if (i < NN) {
        int v = excl[i] + boff;
        rowptr[i] = v;
        cursor[i] = v;
    }
    if (i == 0) rowptr[NN] = NE;
}

// ---------------- edge placement: ssrc sorted by dst ----------------
__global__ void k_fill(const int* __restrict__ src, const int* __restrict__ dst,
                       int* __restrict__ cursor, int* __restrict__ ssrc) {
    int e = blockIdx.x * 256 + threadIdx.x;
    if (e >= NE) return;
    int d = dst[e];
    int pos = atomicAdd(cursor + d, 1);
    ssrc[pos] = src[e];
}

// ---------------- fused gather + layer-1 GEMM + layer-2 projection --------------------
// Phase A: block gather-means its 32 nodes' neighbor x rows (bf16) into LDS
//          (row stride 68 uints -> 2-way bank aliasing, free per m136).
// Phase B: MFMA K-loop; ct 0..3 A-frags from LDS (agg half), ct 4..7 from global xbf.
// Epilogue: h1 = relu(acc+b1l) stays in registers; project onto pq -> per-node scalars
//           g (to be gathered) and u (self term). h1 never materialized.
// Layouts (m89/m91-verified): A-frag A[m=lane&15][k=quad*8+j]; C/D col=lane&15, row=quad*4+reg.
__global__ __launch_bounds__(256) void k_gemm1f(const uint* __restrict__ xbf,
                                                const int* __restrict__ rowptr,
                                                const int* __restrict__ ssrc,
                                                const ushort* __restrict__ Bp,
                                                const float* __restrict__ bias,
                                                const float* __restrict__ pq,
                                                float2* __restrict__ g2,
                                                float2* __restrict__ u2) {
    const int NTW = 4;
    __shared__ uint aggs[32][68];      // 32 rows x 64 uints, +4 pad
    __shared__ float red[4][4][32];
    int wave = threadIdx.x >> 6;
    int lane = threadIdx.x & 63;
    int quad = lane >> 4;
    int l15 = lane & 15;
    int mbase = blockIdx.x * 32;

    // ---- Phase A: gather-mean, wave handles 8 nodes ----
    for (int ln = wave * 8; ln < wave * 8 + 8; ln++) {
        int m = mbase + ln;
        int r0e = 0, r1e = 0;
        if (m < NN) { r0e = rowptr[m]; r1e = rowptr[m + 1]; }
        float ax0 = 0.f, ay0 = 0.f, ax1 = 0.f, ay1 = 0.f;
        float ax2 = 0.f, ay2 = 0.f, ax3 = 0.f, ay3 = 0.f;
        int e = r0e;
        for (; e + 4 <= r1e; e += 4) {
            uint v0 = xbf[(size_t)ssrc[e]     * 64 + lane];
            uint v1 = xbf[(size_t)ssrc[e + 1] * 64 + lane];
            uint v2 = xbf[(size_t)ssrc[e + 2] * 64 + lane];
            uint v3 = xbf[(size_t)ssrc[e + 3] * 64 + lane];
            ax0 += bf2f(v0 & 0xffffu); ay0 += bf2f(v0 >> 16);
            ax1 += bf2f(v1 & 0xffffu); ay1 += bf2f(v1 >> 16);
            ax2 += bf2f(v2 & 0xffffu); ay2 += bf2f(v2 >> 16);
            ax3 += bf2f(v3 & 0xffffu); ay3 += bf2f(v3 >> 16);
        }
        for (; e < r1e; e++) {
            uint v = xbf[(size_t)ssrc[e] * 64 + lane];
            ax0 += bf2f(v & 0xffffu); ay0 += bf2f(v >> 16);
        }
        float ax = (ax0 + ax1) + (ax2 + ax3);
        float ay = (ay0 + ay1) + (ay2 + ay3);
        float sc = 1.0f / fmaxf((float)(r1e - r0e), 1.0f);
        aggs[ln][lane] = (uint)f2bf(ax * sc) | ((uint)f2bf(ay * sc) << 16);
    }
    __syncthreads();

    // ---- Phase B: MFMA K-loop ----
    int r0g = mbase + l15;       if (r0g >= NN) r0g = NN - 1;
    int r1g = mbase + 16 + l15;  if (r1g >= NN) r1g = NN - 1;
    f32x4 acc0[NTW], acc1[NTW];
#pragma unroll
    for (int i = 0; i < NTW; i++) {
        acc0[i] = (f32x4){0.f, 0.f, 0.f, 0.f};
        acc1[i] = (f32x4){0.f, 0.f, 0.f, 0.f};
    }
    const bf16x8* bp = (const bf16x8*)Bp;
#pragma unroll
    for (int ct = 0; ct < 4; ct++) {  // agg half from LDS
        bf16x8 a0 = *(const bf16x8*)&aggs[l15][ct * 16 + quad * 4];
        bf16x8 a1 = *(const bf16x8*)&aggs[16 + l15][ct * 16 + quad * 4];
#pragma unroll
        for (int ntl = 0; ntl < NTW; ntl++) {
            int nt = wave * NTW + ntl;
            bf16x8 b = bp[(ct * 16 + nt) * 64 + lane];
            acc0[ntl] = __builtin_amdgcn_mfma_f32_16x16x32_bf16(a0, b, acc0[ntl], 0, 0, 0);
            acc1[ntl] = __builtin_amdgcn_mfma_f32_16x16x32_bf16(a1, b, acc1[ntl], 0, 0, 0);
        }
    }
    const ushort* xb = (const ushort*)xbf;
#pragma unroll
    for (int ct = 4; ct < 8; ct++) {  // x half from global
        bf16x8 a0 = *(const bf16x8*)(xb + (size_t)r0g * 128 + (ct - 4) * 32 + quad * 8);
        bf16x8 a1 = *(const bf16x8*)(xb + (size_t)r1g * 128 + (ct - 4) * 32 + quad * 8);
#pragma unroll
        for (int ntl = 0; ntl < NTW; ntl++) {
            int nt = wave * NTW + ntl;
            bf16x8 b = bp[(ct * 16 + nt) * 64 + lane];
            acc0[ntl] = __builtin_amdgcn_mfma_f32_16x16x32_bf16(a0, b, acc0[ntl], 0, 0, 0);
            acc1[ntl] = __builtin_amdgcn_mfma_f32_16x16x32_bf16(a1, b, acc1[ntl], 0, 0, 0);
        }
    }

    // ---- epilogue: relu + project onto pq ----
    float pga[2][4] = {{0,0,0,0},{0,0,0,0}}, pgb[2][4] = {{0,0,0,0},{0,0,0,0}};
    float pua[2][4] = {{0,0,0,0},{0,0,0,0}}, pub[2][4] = {{0,0,0,0},{0,0,0,0}};
#pragma unroll
    for (int ntl = 0; ntl < NTW; ntl++) {
        int col = (wave * NTW + ntl) * 16 + l15;
        float bv = bias[col];
        float wpa = pq[col], wpb = pq[256 + col];
        float wqa = pq[512 + col], wqb = pq[768 + col];
#pragma unroll
        for (int reg = 0; reg < 4; reg++) {
            float v0 = acc0[ntl][reg] + bv;  v0 = v0 > 0.f ? v0 : 0.f;
            float v1 = acc1[ntl][reg] + bv;  v1 = v1 > 0.f ? v1 : 0.f;
            pga[0][reg] += v0 * wpa;  pgb[0][reg] += v0 * wpb;
            pua[0][reg] += v0 * wqa;  pub[0][reg] += v0 * wqb;
            pga[1][reg] += v1 * wpa;  pgb[1][reg] += v1 * wpb;
            pua[1][reg] += v1 * wqa;  pub[1][reg] += v1 * wqb;
        }
    }
#pragma unroll
    for (int off = 1; off < 16; off <<= 1) {
#pragma unroll
        for (int rt = 0; rt < 2; rt++) {
#pragma unroll
            for (int reg = 0; reg < 4; reg++) {
                pga[rt][reg] += __shfl_xor(pga[rt][reg], off, 64);
                pgb[rt][reg] += __shfl_xor(pgb[rt][reg], off, 64);
                pua[rt][reg] += __shfl_xor(pua[rt][reg], off, 64);
                pub[rt][reg] += __shfl_xor(pub[rt][reg], off, 64);
            }
        }
    }
    if (l15 == 0) {
#pragma unroll
        for (int rt = 0; rt < 2; rt++) {
#pragma unroll
            for (int reg = 0; reg < 4; reg++) {
                int row = rt * 16 + quad * 4 + reg;
                red[0][wave][row] = pga[rt][reg];
                red[1][wave][row] = pgb[rt][reg];
                red[2][wave][row] = pua[rt][reg];
                red[3][wave][row] = pub[rt][reg];
            }
        }
    }
    __syncthreads();
    if (threadIdx.x < 32) {
        int row = threadIdx.x;
        int m = mbase + row;
        if (m < NN) {
            float ga = (red[0][0][row] + red[0][1][row]) + (red[0][2][row] + red[0][3][row]);
            float gb = (red[1][0][row] + red[1][1][row]) + (red[1][2][row] + red[1][3][row]);
            float ua = (red[2][0][row] + red[2][1][row]) + (red[2][2][row] + red[2][3][row]);
            float ub = (red[3][0][row] + red[3][1][row]) + (red[3][2][row] + red[3][3][row]);
            g2[m] = make_float2(ga, gb);
            u2[m] = make_float2(ua, ub);
        }
    }
}

// ---------------- scalar gather-mean + final add: sa/sb per node ----------------------
__global__ void k_sagg(const float2* __restrict__ g2, const float2* __restrict__ u2,
                       const int* __restrict__ rowptr, const int* __restrict__ ssrc,
                       const float* __restrict__ cab,
                       float* __restrict__ sa, float* __restrict__ sb) {
    int n = blockIdx.x * 256 + threadIdx.x;
    if (n >= NN) return;
    int r0 = rowptr[n], r1 = rowptr[n + 1];
    float a0 = 0.f, b0 = 0.f, a1 = 0.f, b1 = 0.f;
    float a2 = 0.f, b2 = 0.f, a3 = 0.f, b3 = 0.f;
    int e = r0;
    for (; e + 4 <= r1; e += 4) {
        float2 v0 = g2[ssrc[e]];
        float2 v1 = g2[ssrc[e + 1]];
        float2 v2 = g2[ssrc[e + 2]];
        float2 v3 = g2[ssrc[e + 3]];
        a0 += v0.x; b0 += v0.y;
        a1 += v1.x; b1 += v1.y;
        a2 += v2.x; b2 += v2.y;
        a3 += v3.x; b3 += v3.y;
    }
    for (; e < r1; e++) {
        float2 v = g2[ssrc[e]];
        a0 += v.x; b0 += v.y;
    }
    float sc = 1.0f / fmaxf((float)(r1 - r0), 1.0f);
    float2 u = u2[n];
    sa[n] = ((a0 + a1) + (a2 + a3)) * sc + u.x + cab[0];
    sb[n] = ((b0 + b1) + (b2 + b3)) * sc + u.y + cab[1];
}

// ---------------- pair scorer: out[p] = sigmoid(sa[a] + sb[b] + blin) ----------------
__global__ void k_pairs(const float* __restrict__ sa, const float* __restrict__ sb,
                        const int* __restrict__ mask, const float* __restrict__ blin,
                        float* __restrict__ out) {
    int p = blockIdx.x * 256 + threadIdx.x;
    if (p >= NP) return;
    int2 m = ((const int2*)mask)[p];
    float v = sa[m.x] + sb[m.y] + blin[0];
    out[p] = 1.0f / (1.0f + __expf(-v));
}

extern "C" void kernel_launch(void* const* d_in, const int* in_sizes, int n_in,
                              void* d_out, int out_size, void* d_ws, size_t ws_size,
                              hipStream_t stream) {
    const float* x    = (const float*)d_in[0];   // [50000,128]
    const int*   ei   = (const int*)  d_in[1];   // [2,600000]
    const int*   mask = (const int*)  d_in[2];   // [200000,2]
    const float* W1l  = (const float*)d_in[3];   // [128,256]
    const float* b1l  = (const float*)d_in[4];   // [256]
    const float* W1r  = (const float*)d_in[5];   // [128,256]
    const float* W2l  = (const float*)d_in[6];   // [256,128]
    const float* b2l  = (const float*)d_in[7];   // [128]
    const float* W2r  = (const float*)d_in[8];   // [256,128]
    const float* Wlin = (const float*)d_in[9];   // [256,1]
    const float* blin = (const float*)d_in[10];  // [1]
    float* out = (float*)d_out;                  // [200000,1]

    const int* src = ei;
    const int* dst = ei + NE;

    char* ws = (char*)d_ws;
    int*    deg    = (int*)(ws);                             // 200 KB
    int*    rowptr = (int*)(ws + (size_t)1 * (1 << 20));
    int*    cursor = (int*)(ws + (size_t)2 * (1 << 20));
    int*    ssrc   = (int*)(ws + (size_t)3 * (1 << 20));     // 2.4 MB
    int*    excl   = (int*)(ws + (size_t)6 * (1 << 20));     // 200 KB
    int*    bsum   = (int*)(ws + (size_t)7 * (1 << 20));     // 196 B
    ushort* Bp1    = (ushort*)(ws + (size_t)8 * (1 << 20));  // 128 KB
    float*  pq     = (float*)(ws + (size_t)9 * (1 << 20));   // 4 KB
    float*  cab    = (float*)(ws + (size_t)9 * (1 << 20) + 65536);
    float*  sa     = (float*)(ws + (size_t)10 * (1 << 20));  // 200 KB
    float*  sb     = (float*)(ws + (size_t)11 * (1 << 20));  // 200 KB
    float2* g2     = (float2*)(ws + (size_t)12 * (1 << 20)); // 400 KB
    float2* u2     = (float2*)(ws + (size_t)13 * (1 << 20)); // 400 KB
    uint*   xbf    = (uint*)(ws + (size_t)14 * (1 << 20));   // [50000,128] bf16 = 12.8 MB

    hipMemsetAsync(deg, 0, (size_t)NN * 4, stream);

    k_pre   <<<(T_CAB + 255) / 256, 256, 0, stream>>>(x, xbf, dst, deg,
                                                      W1l, W1r, Bp1,
                                                      W2l, W2r, Wlin, b2l, pq, cab);
    k_scan1 <<<NB_SCAN, 1024, 0, stream>>>(deg, excl, bsum);
    k_scan23<<<NB_SCAN, 1024, 0, stream>>>(excl, bsum, rowptr, cursor);
    k_fill  <<<(NE + 255) / 256, 256, 0, stream>>>(src, dst, cursor, ssrc);

    k_gemm1f<<<(NN + 31) / 32, 256, 0, stream>>>(xbf, rowptr, ssrc, Bp1, b1l,
                                                 pq, g2, u2);
    k_sagg  <<<(NN + 255) / 256, 256, 0, stream>>>(g2, u2, rowptr, ssrc, cab, sa, sb);
    k_pairs <<<(NP + 255) / 256, 256, 0, stream>>>(sa, sb, mask, blin, out);
}

// Round 10
// 224.817 us; speedup vs baseline: 1.1390x; 1.1390x over previous
//
#include <hip/hip_runtime.h>
#include <math.h>

#define NN 50000
#define NE 600000
#define NP 200000
#define NB_SCAN 49  // ceil(NN / 1024)

typedef unsigned int uint;
typedef unsigned short ushort;
typedef __attribute__((ext_vector_type(8))) short bf16x8;
typedef __attribute__((ext_vector_type(4))) float f32x4;

// ---- bf16 helpers (RNE) ----
__device__ __forceinline__ ushort f2bf(float f) {
    uint u = __float_as_uint(f);
    uint r = (u + 0x7FFFu + ((u >> 16) & 1u)) >> 16;
    return (ushort)r;
}
__device__ __forceinline__ float bf2f(uint lo16) {
    return __uint_as_float(lo16 << 16);
}

__device__ __forceinline__ int wave_iscan(int v, int lane) {
#pragma unroll
    for (int off = 1; off < 64; off <<= 1) {
        int t = __shfl_up(v, off, 64);
        if (lane >= off) v += t;
    }
    return v;
}

// ---- W swizzle into MFMA B-operand layout (bf16) ----
// Bp[((ct*(N/16)+nt)*64 + lane)*8 + j] = Wcat[ct*32 + (lane>>4)*8 + j][nt*16 + (lane&15)]
template <int K, int N>
__device__ __forceinline__ void prepB_one(int idx, const float* __restrict__ Wt,
                                          const float* __restrict__ Wb,
                                          ushort* __restrict__ Bp) {
    int lane = idx & 63;
    int nt = (idx >> 6) % (N / 16);
    int ct = idx / (64 * (N / 16));
    int n = nt * 16 + (lane & 15);
    int kb = ct * 32 + (lane >> 4) * 8;
#pragma unroll
    for (int j = 0; j < 8; j++) {
        int k = kb + j;
        float w = (k < K / 2) ? Wt[(size_t)k * N + n] : Wb[(size_t)(k - K / 2) * N + n];
        Bp[(size_t)idx * 8 + j] = f2bf(w);
    }
}

// ---------------- fused prologue ----------------
// ranges: x->bf16 (float4) | deg histogram | Bp1 swizzle | pq vectors | cab scalars
// pq[0:256]=W2l@wa, pq[256:512]=W2l@wb, pq[512:768]=W2r@wa, pq[768:1024]=W2r@wb
#define T_PREP (NN * 32)
#define T_DEG  (T_PREP + NE)
#define T_B1   (T_DEG + 8192)
#define T_PQ   (T_B1 + 1024)
#define T_CAB  (T_PQ + 2)
__global__ void k_pre(const float* __restrict__ x, uint* __restrict__ A1u,
                      const int* __restrict__ dst, int* __restrict__ deg,
                      const float* __restrict__ W1l, const float* __restrict__ W1r,
                      ushort* __restrict__ Bp1,
                      const float* __restrict__ W2l, const float* __restrict__ W2r,
                      const float* __restrict__ Wlin, const float* __restrict__ b2l,
                      float* __restrict__ pq, float* __restrict__ cab) {
    int t = blockIdx.x * 256 + threadIdx.x;
    if (t < T_PREP) {
        int n = t >> 5, c4 = t & 31;
        float4 v = *(const float4*)(x + (size_t)n * 128 + c4 * 4);
        uint2 o;
        o.x = (uint)f2bf(v.x) | ((uint)f2bf(v.y) << 16);
        o.y = (uint)f2bf(v.z) | ((uint)f2bf(v.w) << 16);
        *(uint2*)(A1u + (size_t)n * 128 + 64 + c4 * 2) = o;  // right half = x
    } else if (t < T_DEG) {
        atomicAdd(deg + dst[t - T_PREP], 1);
    } else if (t < T_B1) {
        prepB_one<256, 256>(t - T_DEG, W1l, W1r, Bp1);
    } else if (t < T_PQ) {
        int idx = t - T_B1;
        int vec = idx >> 8;          // 0..3
        int k = idx & 255;
        const float* W = (vec < 2) ? W2l : W2r;    // [256,128]
        const float* wl = Wlin + (vec & 1) * 128;  // wa or wb
        float s = 0.f;
#pragma unroll 4
        for (int j = 0; j < 128; j++) s += W[(size_t)k * 128 + j] * wl[j];
        pq[idx] = s;
    } else if (t < T_CAB) {
        int i = t - T_PQ;
        float s = 0.f;
        for (int j = 0; j < 128; j++) s += b2l[j] * Wlin[i * 128 + j];
        cab[i] = s;
    }
}

// ---------------- scan phase 1: per-block exclusive values + block sums ----------------
__global__ __launch_bounds__(1024) void k_scan1(const int* __restrict__ deg,
                                                int* __restrict__ excl,
                                                int* __restrict__ bsum) {
    int tid = threadIdx.x;
    int i = blockIdx.x * 1024 + tid;
    int lane = tid & 63, wid = tid >> 6;
    int v = (i < NN) ? deg[i] : 0;
    int incl = wave_iscan(v, lane);
    __shared__ int wt[16];
    if (lane == 63) wt[wid] = incl;
    __syncthreads();
    if (tid < 16) {
        int w = wt[tid];
#pragma unroll
        for (int off = 1; off < 16; off <<= 1) {
            int t = __shfl_up(w, off, 64);
            if (tid >= off) w += t;
        }
        wt[tid] = w;
    }
    __syncthreads();
    int base = (wid > 0) ? wt[wid - 1] : 0;
    if (i < NN) excl[i] = incl - v + base;
    if (tid == 0) bsum[blockIdx.x] = wt[15];
}

// ---------------- scan phases 2+3 merged: each block rescans bsum (49 ints, free) ------
__global__ __launch_bounds__(1024) void k_scan23(const int* __restrict__ excl,
                                                 const int* __restrict__ bsum,
                                                 int* __restrict__ rowptr,
                                                 int* __restrict__ cursor) {
    __shared__ int boff;
    int tid = threadIdx.x;
    if (tid < 64) {
        int v = (tid < NB_SCAN) ? bsum[tid] : 0;
        int incl = wave_iscan(v, tid);
        if (tid == (int)blockIdx.x) boff = incl - v;  // exclusive prefix at this block
    }
    __syncthreads();
    int i = blockIdx.x * 1024 + tid;
    if (i < NN) {
        int v = excl[i] + boff;
        rowptr[i] = v;
        cursor[i] = v;
    }
    if (i == 0) rowptr[NN] = NE;
}

// ---------------- edge placement: ssrc sorted by dst ----------------
__global__ void k_fill(const int* __restrict__ src, const int* __restrict__ dst,
                       int* __restrict__ cursor, int* __restrict__ ssrc) {
    int e = blockIdx.x * 256 + threadIdx.x;
    if (e >= NE) return;
    int d = dst[e];
    int pos = atomicAdd(cursor + d, 1);
    ssrc[pos] = src[e];
}

// ---------------- gather-mean of x(bf16) -> A1 left half; 8 edges in flight ------------
// wave per node: max TLP (50000 waves), coalesced 256 B row reads
__global__ void k_agg1(uint* __restrict__ A1u, const int* __restrict__ rowptr,
                       const int* __restrict__ ssrc) {
    int t = blockIdx.x * 256 + threadIdx.x;
    int n = t >> 6;
    if (n >= NN) return;
    int lane = t & 63;
    int r0 = rowptr[n], r1 = rowptr[n + 1];
    float ax0 = 0.f, ay0 = 0.f, ax1 = 0.f, ay1 = 0.f;
    float ax2 = 0.f, ay2 = 0.f, ax3 = 0.f, ay3 = 0.f;
    int e = r0;
    for (; e + 8 <= r1; e += 8) {
        uint v0 = A1u[(size_t)ssrc[e]     * 128 + 64 + lane];
        uint v1 = A1u[(size_t)ssrc[e + 1] * 128 + 64 + lane];
        uint v2 = A1u[(size_t)ssrc[e + 2] * 128 + 64 + lane];
        uint v3 = A1u[(size_t)ssrc[e + 3] * 128 + 64 + lane];
        uint v4 = A1u[(size_t)ssrc[e + 4] * 128 + 64 + lane];
        uint v5 = A1u[(size_t)ssrc[e + 5] * 128 + 64 + lane];
        uint v6 = A1u[(size_t)ssrc[e + 6] * 128 + 64 + lane];
        uint v7 = A1u[(size_t)ssrc[e + 7] * 128 + 64 + lane];
        ax0 += bf2f(v0 & 0xffffu); ay0 += bf2f(v0 >> 16);
        ax1 += bf2f(v1 & 0xffffu); ay1 += bf2f(v1 >> 16);
        ax2 += bf2f(v2 & 0xffffu); ay2 += bf2f(v2 >> 16);
        ax3 += bf2f(v3 & 0xffffu); ay3 += bf2f(v3 >> 16);
        ax0 += bf2f(v4 & 0xffffu); ay0 += bf2f(v4 >> 16);
        ax1 += bf2f(v5 & 0xffffu); ay1 += bf2f(v5 >> 16);
        ax2 += bf2f(v6 & 0xffffu); ay2 += bf2f(v6 >> 16);
        ax3 += bf2f(v7 & 0xffffu); ay3 += bf2f(v7 >> 16);
    }
    for (; e < r1; e++) {
        uint v = A1u[(size_t)ssrc[e] * 128 + 64 + lane];
        ax0 += bf2f(v & 0xffffu); ay0 += bf2f(v >> 16);
    }
    float ax = (ax0 + ax1) + (ax2 + ax3);
    float ay = (ay0 + ay1) + (ay2 + ay3);
    float sc = 1.0f / fmaxf((float)(r1 - r0), 1.0f);
    A1u[(size_t)n * 128 + lane] = (uint)f2bf(ax * sc) | ((uint)f2bf(ay * sc) << 16);
}

// ---------------- layer-1 GEMM + fused layer-2 projection -----------------------------
// h1 = relu(A1@[W1l;W1r]+b1l) lives only in registers. Epilogue computes 4 per-node
// scalars: g_a=h1.pa, g_b=h1.pb (gathered later), u_a=h1.qa, u_b=h1.qb.
// Block = 4 waves x (32 rows x 256 cols); wave owns 64 cols, 2 row-tiles.
// Layouts (m89/m91-verified): A-frag A[m=lane&15][k=quad*8+j]; C/D col=lane&15, row=quad*4+reg.
__global__ __launch_bounds__(256) void k_gemm1(const ushort* __restrict__ A,
                                               const ushort* __restrict__ Bp,
                                               const float* __restrict__ bias,
                                               const float* __restrict__ pq,
                                               float2* __restrict__ g2,
                                               float2* __restrict__ u2) {
    const int K = 256, NTW = 4;
    int wave = threadIdx.x >> 6;
    int lane = threadIdx.x & 63;
    int quad = lane >> 4;
    int l15 = lane & 15;
    int mbase = blockIdx.x * 32;
    int r0 = mbase + l15;       if (r0 >= NN) r0 = NN - 1;
    int r1 = mbase + 16 + l15;  if (r1 >= NN) r1 = NN - 1;
    f32x4 acc0[NTW], acc1[NTW];
#pragma unroll
    for (int i = 0; i < NTW; i++) {
        acc0[i] = (f32x4){0.f, 0.f, 0.f, 0.f};
        acc1[i] = (f32x4){0.f, 0.f, 0.f, 0.f};
    }
    const bf16x8* bp = (const bf16x8*)Bp;
#pragma unroll
    for (int ct = 0; ct < K / 32; ct++) {
        bf16x8 a0 = *(const bf16x8*)(A + (size_t)r0 * K + ct * 32 + quad * 8);
        bf16x8 a1 = *(const bf16x8*)(A + (size_t)r1 * K + ct * 32 + quad * 8);
#pragma unroll
        for (int ntl = 0; ntl < NTW; ntl++) {
            int nt = wave * NTW + ntl;
            bf16x8 b = bp[(ct * 16 + nt) * 64 + lane];
            acc0[ntl] = __builtin_amdgcn_mfma_f32_16x16x32_bf16(a0, b, acc0[ntl], 0, 0, 0);
            acc1[ntl] = __builtin_amdgcn_mfma_f32_16x16x32_bf16(a1, b, acc1[ntl], 0, 0, 0);
        }
    }
    // epilogue: relu + project onto pq
    float pga[2][4] = {{0,0,0,0},{0,0,0,0}}, pgb[2][4] = {{0,0,0,0},{0,0,0,0}};
    float pua[2][4] = {{0,0,0,0},{0,0,0,0}}, pub[2][4] = {{0,0,0,0},{0,0,0,0}};
#pragma unroll
    for (int ntl = 0; ntl < NTW; ntl++) {
        int col = (wave * NTW + ntl) * 16 + l15;
        float bv = bias[col];
        float wpa = pq[col], wpb = pq[256 + col];
        float wqa = pq[512 + col], wqb = pq[768 + col];
#pragma unroll
        for (int reg = 0; reg < 4; reg++) {
            float v0 = acc0[ntl][reg] + bv;  v0 = v0 > 0.f ? v0 : 0.f;
            float v1 = acc1[ntl][reg] + bv;  v1 = v1 > 0.f ? v1 : 0.f;
            pga[0][reg] += v0 * wpa;  pgb[0][reg] += v0 * wpb;
            pua[0][reg] += v0 * wqa;  pub[0][reg] += v0 * wqb;
            pga[1][reg] += v1 * wpa;  pgb[1][reg] += v1 * wpb;
            pua[1][reg] += v1 * wqa;  pub[1][reg] += v1 * wqb;
        }
    }
#pragma unroll
    for (int off = 1; off < 16; off <<= 1) {
#pragma unroll
        for (int rt = 0; rt < 2; rt++) {
#pragma unroll
            for (int reg = 0; reg < 4; reg++) {
                pga[rt][reg] += __shfl_xor(pga[rt][reg], off, 64);
                pgb[rt][reg] += __shfl_xor(pgb[rt][reg], off, 64);
                pua[rt][reg] += __shfl_xor(pua[rt][reg], off, 64);
                pub[rt][reg] += __shfl_xor(pub[rt][reg], off, 64);
            }
        }
    }
    __shared__ float red[4][4][32];
    if (l15 == 0) {
#pragma unroll
        for (int rt = 0; rt < 2; rt++) {
#pragma unroll
            for (int reg = 0; reg < 4; reg++) {
                int row = rt * 16 + quad * 4 + reg;
                red[0][wave][row] = pga[rt][reg];
                red[1][wave][row] = pgb[rt][reg];
                red[2][wave][row] = pua[rt][reg];
                red[3][wave][row] = pub[rt][reg];
            }
        }
    }
    __syncthreads();
    if (threadIdx.x < 32) {
        int row = threadIdx.x;
        int m = mbase + row;
        if (m < NN) {
            float ga = (red[0][0][row] + red[0][1][row]) + (red[0][2][row] + red[0][3][row]);
            float gb = (red[1][0][row] + red[1][1][row]) + (red[1][2][row] + red[1][3][row]);
            float ua = (red[2][0][row] + red[2][1][row]) + (red[2][2][row] + red[2][3][row]);
            float ub = (red[3][0][row] + red[3][1][row]) + (red[3][2][row] + red[3][3][row]);
            g2[m] = make_float2(ga, gb);
            u2[m] = make_float2(ua, ub);
        }
    }
}

// ---------------- scalar gather-mean + final add: sa/sb per node ----------------------
__global__ void k_sagg(const float2* __restrict__ g2, const float2* __restrict__ u2,
                       const int* __restrict__ rowptr, const int* __restrict__ ssrc,
                       const float* __restrict__ cab,
                       float* __restrict__ sa, float* __restrict__ sb) {
    int n = blockIdx.x * 256 + threadIdx.x;
    if (n >= NN) return;
    int r0 = rowptr[n], r1 = rowptr[n + 1];
    float a0 = 0.f, b0 = 0.f, a1 = 0.f, b1 = 0.f;
    float a2 = 0.f, b2 = 0.f, a3 = 0.f, b3 = 0.f;
    int e = r0;
    for (; e + 4 <= r1; e += 4) {
        float2 v0 = g2[ssrc[e]];
        float2 v1 = g2[ssrc[e + 1]];
        float2 v2 = g2[ssrc[e + 2]];
        float2 v3 = g2[ssrc[e + 3]];
        a0 += v0.x; b0 += v0.y;
        a1 += v1.x; b1 += v1.y;
        a2 += v2.x; b2 += v2.y;
        a3 += v3.x; b3 += v3.y;
    }
    for (; e < r1; e++) {
        float2 v = g2[ssrc[e]];
        a0 += v.x; b0 += v.y;
    }
    float sc = 1.0f / fmaxf((float)(r1 - r0), 1.0f);
    float2 u = u2[n];
    sa[n] = ((a0 + a1) + (a2 + a3)) * sc + u.x + cab[0];
    sb[n] = ((b0 + b1) + (b2 + b3)) * sc + u.y + cab[1];
}

// ---------------- pair scorer: out[p] = sigmoid(sa[a] + sb[b] + blin) ----------------
__global__ void k_pairs(const float* __restrict__ sa, const float* __restrict__ sb,
                        const int* __restrict__ mask, const float* __restrict__ blin,
                        float* __restrict__ out) {
    int p = blockIdx.x * 256 + threadIdx.x;
    if (p >= NP) return;
    int2 m = ((const int2*)mask)[p];
    float v = sa[m.x] + sb[m.y] + blin[0];
    out[p] = 1.0f / (1.0f + __expf(-v));
}

extern "C" void kernel_launch(void* const* d_in, const int* in_sizes, int n_in,
                              void* d_out, int out_size, void* d_ws, size_t ws_size,
                              hipStream_t stream) {
    const float* x    = (const float*)d_in[0];   // [50000,128]
    const int*   ei   = (const int*)  d_in[1];   // [2,600000]
    const int*   mask = (const int*)  d_in[2];   // [200000,2]
    const float* W1l  = (const float*)d_in[3];   // [128,256]
    const float* b1l  = (const float*)d_in[4];   // [256]
    const float* W1r  = (const float*)d_in[5];   // [128,256]
    const float* W2l  = (const float*)d_in[6];   // [256,128]
    const float* b2l  = (const float*)d_in[7];   // [128]
    const float* W2r  = (const float*)d_in[8];   // [256,128]
    const float* Wlin = (const float*)d_in[9];   // [256,1]
    const float* blin = (const float*)d_in[10];  // [1]
    float* out = (float*)d_out;                  // [200000,1]

    const int* src = ei;
    const int* dst = ei + NE;

    char* ws = (char*)d_ws;
    int*    deg    = (int*)(ws);                             // 200 KB
    int*    rowptr = (int*)(ws + (size_t)1 * (1 << 20));
    int*    cursor = (int*)(ws + (size_t)2 * (1 << 20));
    int*    ssrc   = (int*)(ws + (size_t)3 * (1 << 20));     // 2.4 MB
    int*    excl   = (int*)(ws + (size_t)6 * (1 << 20));     // 200 KB
    int*    bsum   = (int*)(ws + (size_t)7 * (1 << 20));     // 196 B
    ushort* Bp1    = (ushort*)(ws + (size_t)8 * (1 << 20));  // 128 KB
    float*  pq     = (float*)(ws + (size_t)9 * (1 << 20));   // 4 KB
    float*  cab    = (float*)(ws + (size_t)9 * (1 << 20) + 65536);
    float*  sa     = (float*)(ws + (size_t)10 * (1 << 20));  // 200 KB
    float*  sb     = (float*)(ws + (size_t)11 * (1 << 20));  // 200 KB
    float2* g2     = (float2*)(ws + (size_t)12 * (1 << 20)); // 400 KB
    float2* u2     = (float2*)(ws + (size_t)13 * (1 << 20)); // 400 KB
    uint*   A1u    = (uint*)(ws + (size_t)14 * (1 << 20));   // [50000,256] bf16 = 25.6 MB

    hipMemsetAsync(deg, 0, (size_t)NN * 4, stream);

    k_pre   <<<(T_CAB + 255) / 256, 256, 0, stream>>>(x, A1u, dst, deg,
                                                      W1l, W1r, Bp1,
                                                      W2l, W2r, Wlin, b2l, pq, cab);
    k_scan1 <<<NB_SCAN, 1024, 0, stream>>>(deg, excl, bsum);
    k_scan23<<<NB_SCAN, 1024, 0, stream>>>(excl, bsum, rowptr, cursor);
    k_fill  <<<(NE + 255) / 256, 256, 0, stream>>>(src, dst, cursor, ssrc);

    k_agg1  <<<NN / 4, 256, 0, stream>>>(A1u, rowptr, ssrc);
    k_gemm1 <<<(NN + 31) / 32, 256, 0, stream>>>((const ushort*)A1u, Bp1, b1l,
                                                 pq, g2, u2);
    k_sagg  <<<(NN + 255) / 256, 256, 0, stream>>>(g2, u2, rowptr, ssrc, cab, sa, sb);
    k_pairs <<<(NP + 255) / 256, 256, 0, stream>>>(sa, sb, mask, blin, out);
}

// Round 11
// 217.097 us; speedup vs baseline: 1.1795x; 1.0356x over previous
//
#include <hip/hip_runtime.h>
#include <math.h>

#define NN 50000
#define NE 600000
#define NP 200000
#define NB_SCAN 49  // ceil(NN / 1024)

typedef unsigned int uint;
typedef unsigned short ushort;
typedef __attribute__((ext_vector_type(8))) short bf16x8;
typedef __attribute__((ext_vector_type(4))) float f32x4;

// ---- bf16 helpers (RNE) ----
__device__ __forceinline__ ushort f2bf(float f) {
    uint u = __float_as_uint(f);
    uint r = (u + 0x7FFFu + ((u >> 16) & 1u)) >> 16;
    return (ushort)r;
}
__device__ __forceinline__ float bf2f(uint lo16) {
    return __uint_as_float(lo16 << 16);
}

__device__ __forceinline__ int wave_iscan(int v, int lane) {
#pragma unroll
    for (int off = 1; off < 64; off <<= 1) {
        int t = __shfl_up(v, off, 64);
        if (lane >= off) v += t;
    }
    return v;
}

// ---- W swizzle into MFMA B-operand layout (bf16) ----
// Bp[((ct*(N/16)+nt)*64 + lane)*8 + j] = Wcat[ct*32 + (lane>>4)*8 + j][nt*16 + (lane&15)]
template <int K, int N>
__device__ __forceinline__ void prepB_one(int idx, const float* __restrict__ Wt,
                                          const float* __restrict__ Wb,
                                          ushort* __restrict__ Bp) {
    int lane = idx & 63;
    int nt = (idx >> 6) % (N / 16);
    int ct = idx / (64 * (N / 16));
    int n = nt * 16 + (lane & 15);
    int kb = ct * 32 + (lane >> 4) * 8;
#pragma unroll
    for (int j = 0; j < 8; j++) {
        int k = kb + j;
        float w = (k < K / 2) ? Wt[(size_t)k * N + n] : Wb[(size_t)(k - K / 2) * N + n];
        Bp[(size_t)idx * 8 + j] = f2bf(w);
    }
}

// ---------------- fused prologue ----------------
// ranges: x->bf16 (float4) | deg histogram | Bp1 swizzle | pq vectors | cab scalars
// pq[0:256]=W2l@wa, pq[256:512]=W2l@wb, pq[512:768]=W2r@wa, pq[768:1024]=W2r@wb
#define T_PREP (NN * 32)
#define T_DEG  (T_PREP + NE)
#define T_B1   (T_DEG + 8192)
#define T_PQ   (T_B1 + 1024)
#define T_CAB  (T_PQ + 2)
__global__ void k_pre(const float* __restrict__ x, uint* __restrict__ A1u,
                      const int* __restrict__ dst, int* __restrict__ deg,
                      const float* __restrict__ W1l, const float* __restrict__ W1r,
                      ushort* __restrict__ Bp1,
                      const float* __restrict__ W2l, const float* __restrict__ W2r,
                      const float* __restrict__ Wlin, const float* __restrict__ b2l,
                      float* __restrict__ pq, float* __restrict__ cab) {
    int t = blockIdx.x * 256 + threadIdx.x;
    if (t < T_PREP) {
        int n = t >> 5, c4 = t & 31;
        float4 v = *(const float4*)(x + (size_t)n * 128 + c4 * 4);
        uint2 o;
        o.x = (uint)f2bf(v.x) | ((uint)f2bf(v.y) << 16);
        o.y = (uint)f2bf(v.z) | ((uint)f2bf(v.w) << 16);
        *(uint2*)(A1u + (size_t)n * 128 + 64 + c4 * 2) = o;  // right half = x
    } else if (t < T_DEG) {
        atomicAdd(deg + dst[t - T_PREP], 1);
    } else if (t < T_B1) {
        prepB_one<256, 256>(t - T_DEG, W1l, W1r, Bp1);
    } else if (t < T_PQ) {
        int idx = t - T_B1;
        int vec = idx >> 8;          // 0..3
        int k = idx & 255;
        const float* W = (vec < 2) ? W2l : W2r;    // [256,128]
        const float* wl = Wlin + (vec & 1) * 128;  // wa or wb
        float s = 0.f;
#pragma unroll 4
        for (int j = 0; j < 128; j++) s += W[(size_t)k * 128 + j] * wl[j];
        pq[idx] = s;
    } else if (t < T_CAB) {
        int i = t - T_PQ;
        float s = 0.f;
        for (int j = 0; j < 128; j++) s += b2l[j] * Wlin[i * 128 + j];
        cab[i] = s;
    }
}

// ---------------- scan phase 1: per-block exclusive values + block sums ----------------
__global__ __launch_bounds__(1024) void k_scan1(const int* __restrict__ deg,
                                                int* __restrict__ excl,
                                                int* __restrict__ bsum) {
    int tid = threadIdx.x;
    int i = blockIdx.x * 1024 + tid;
    int lane = tid & 63, wid = tid >> 6;
    int v = (i < NN) ? deg[i] : 0;
    int incl = wave_iscan(v, lane);
    __shared__ int wt[16];
    if (lane == 63) wt[wid] = incl;
    __syncthreads();
    if (tid < 16) {
        int w = wt[tid];
#pragma unroll
        for (int off = 1; off < 16; off <<= 1) {
            int t = __shfl_up(w, off, 64);
            if (tid >= off) w += t;
        }
        wt[tid] = w;
    }
    __syncthreads();
    int base = (wid > 0) ? wt[wid - 1] : 0;
    if (i < NN) excl[i] = incl - v + base;
    if (tid == 0) bsum[blockIdx.x] = wt[15];
}

// ---------------- scan phases 2+3 merged: each block rescans bsum (49 ints, free) ------
__global__ __launch_bounds__(1024) void k_scan23(const int* __restrict__ excl,
                                                 const int* __restrict__ bsum,
                                                 int* __restrict__ rowptr,
                                                 int* __restrict__ cursor) {
    __shared__ int boff;
    int tid = threadIdx.x;
    if (tid < 64) {
        int v = (tid < NB_SCAN) ? bsum[tid] : 0;
        int incl = wave_iscan(v, tid);
        if (tid == (int)blockIdx.x) boff = incl - v;  // exclusive prefix at this block
    }
    __syncthreads();
    int i = blockIdx.x * 1024 + tid;
    if (i < NN) {
        int v = excl[i] + boff;
        rowptr[i] = v;
        cursor[i] = v;
    }
    if (i == 0) rowptr[NN] = NE;
}

// ---------------- edge placement: ssrc sorted by dst ----------------
__global__ void k_fill(const int* __restrict__ src, const int* __restrict__ dst,
                       int* __restrict__ cursor, int* __restrict__ ssrc) {
    int e = blockIdx.x * 256 + threadIdx.x;
    if (e >= NE) return;
    int d = dst[e];
    int pos = atomicAdd(cursor + d, 1);
    ssrc[pos] = src[e];
}

// ---------------- gather-mean of x(bf16) -> A1 left half ------------------------------
// wave per node; 16 lanes x uint4 per row -> 4 edges per wave-load (1 KB/instr),
// 2 loads in flight (8 edges). Cross-group reduce via shfl_xor(16,32); lanes g==0 store.
__global__ void k_agg1(uint* __restrict__ A1u, const int* __restrict__ rowptr,
                       const int* __restrict__ ssrc) {
    int t = blockIdx.x * 256 + threadIdx.x;
    int n = t >> 6;
    if (n >= NN) return;
    int lane = t & 63;
    int g = lane >> 4;      // edge group 0..3
    int s = lane & 15;      // 16-byte chunk within row (cols 8s..8s+7)
    int r0 = rowptr[n], r1 = rowptr[n + 1];
    float a0[8] = {0.f, 0.f, 0.f, 0.f, 0.f, 0.f, 0.f, 0.f};
    float a1[8] = {0.f, 0.f, 0.f, 0.f, 0.f, 0.f, 0.f, 0.f};
    int e = r0;
    for (; e + 8 <= r1; e += 8) {
        int sA = ssrc[e + g];
        int sB = ssrc[e + 4 + g];
        uint4 vA = *(const uint4*)(A1u + (size_t)sA * 128 + 64 + s * 4);
        uint4 vB = *(const uint4*)(A1u + (size_t)sB * 128 + 64 + s * 4);
        a0[0] += bf2f(vA.x & 0xffffu); a0[1] += bf2f(vA.x >> 16);
        a0[2] += bf2f(vA.y & 0xffffu); a0[3] += bf2f(vA.y >> 16);
        a0[4] += bf2f(vA.z & 0xffffu); a0[5] += bf2f(vA.z >> 16);
        a0[6] += bf2f(vA.w & 0xffffu); a0[7] += bf2f(vA.w >> 16);
        a1[0] += bf2f(vB.x & 0xffffu); a1[1] += bf2f(vB.x >> 16);
        a1[2] += bf2f(vB.y & 0xffffu); a1[3] += bf2f(vB.y >> 16);
        a1[4] += bf2f(vB.z & 0xffffu); a1[5] += bf2f(vB.z >> 16);
        a1[6] += bf2f(vB.w & 0xffffu); a1[7] += bf2f(vB.w >> 16);
    }
    if (e + 4 <= r1) {
        int sA = ssrc[e + g];
        uint4 vA = *(const uint4*)(A1u + (size_t)sA * 128 + 64 + s * 4);
        a0[0] += bf2f(vA.x & 0xffffu); a0[1] += bf2f(vA.x >> 16);
        a0[2] += bf2f(vA.y & 0xffffu); a0[3] += bf2f(vA.y >> 16);
        a0[4] += bf2f(vA.z & 0xffffu); a0[5] += bf2f(vA.z >> 16);
        a0[6] += bf2f(vA.w & 0xffffu); a0[7] += bf2f(vA.w >> 16);
        e += 4;
    }
    int rem = r1 - e;  // 0..3
    if (g < rem) {
        int sB = ssrc[e + g];
        uint4 vB = *(const uint4*)(A1u + (size_t)sB * 128 + 64 + s * 4);
        a1[0] += bf2f(vB.x & 0xffffu); a1[1] += bf2f(vB.x >> 16);
        a1[2] += bf2f(vB.y & 0xffffu); a1[3] += bf2f(vB.y >> 16);
        a1[4] += bf2f(vB.z & 0xffffu); a1[5] += bf2f(vB.z >> 16);
        a1[6] += bf2f(vB.w & 0xffffu); a1[7] += bf2f(vB.w >> 16);
    }
    float ax[8];
#pragma unroll
    for (int j = 0; j < 8; j++) ax[j] = a0[j] + a1[j];
    // fold the 4 edge-groups (lanes differing in bits 4,5 hold same cols)
#pragma unroll
    for (int j = 0; j < 8; j++) {
        ax[j] += __shfl_xor(ax[j], 16, 64);
        ax[j] += __shfl_xor(ax[j], 32, 64);
    }
    if (g == 0) {
        float sc = 1.0f / fmaxf((float)(r1 - r0), 1.0f);
        uint4 o;
        o.x = (uint)f2bf(ax[0] * sc) | ((uint)f2bf(ax[1] * sc) << 16);
        o.y = (uint)f2bf(ax[2] * sc) | ((uint)f2bf(ax[3] * sc) << 16);
        o.z = (uint)f2bf(ax[4] * sc) | ((uint)f2bf(ax[5] * sc) << 16);
        o.w = (uint)f2bf(ax[6] * sc) | ((uint)f2bf(ax[7] * sc) << 16);
        *(uint4*)(A1u + (size_t)n * 128 + s * 4) = o;
    }
}

// ---------------- layer-1 GEMM + fused layer-2 projection -----------------------------
// h1 = relu(A1@[W1l;W1r]+b1l) lives only in registers. Epilogue computes 4 per-node
// scalars: g_a=h1.pa, g_b=h1.pb (gathered later), u_a=h1.qa, u_b=h1.qb.
// Block = 4 waves x (32 rows x 256 cols); wave owns 64 cols, 2 row-tiles.
// Layouts (m89/m91-verified): A-frag A[m=lane&15][k=quad*8+j]; C/D col=lane&15, row=quad*4+reg.
__global__ __launch_bounds__(256) void k_gemm1(const ushort* __restrict__ A,
                                               const ushort* __restrict__ Bp,
                                               const float* __restrict__ bias,
                                               const float* __restrict__ pq,
                                               float2* __restrict__ g2,
                                               float2* __restrict__ u2) {
    const int K = 256, NTW = 4;
    int wave = threadIdx.x >> 6;
    int lane = threadIdx.x & 63;
    int quad = lane >> 4;
    int l15 = lane & 15;
    int mbase = blockIdx.x * 32;
    int r0 = mbase + l15;       if (r0 >= NN) r0 = NN - 1;
    int r1 = mbase + 16 + l15;  if (r1 >= NN) r1 = NN - 1;
    f32x4 acc0[NTW], acc1[NTW];
#pragma unroll
    for (int i = 0; i < NTW; i++) {
        acc0[i] = (f32x4){0.f, 0.f, 0.f, 0.f};
        acc1[i] = (f32x4){0.f, 0.f, 0.f, 0.f};
    }
    const bf16x8* bp = (const bf16x8*)Bp;
#pragma unroll
    for (int ct = 0; ct < K / 32; ct++) {
        bf16x8 a0 = *(const bf16x8*)(A + (size_t)r0 * K + ct * 32 + quad * 8);
        bf16x8 a1 = *(const bf16x8*)(A + (size_t)r1 * K + ct * 32 + quad * 8);
#pragma unroll
        for (int ntl = 0; ntl < NTW; ntl++) {
            int nt = wave * NTW + ntl;
            bf16x8 b = bp[(ct * 16 + nt) * 64 + lane];
            acc0[ntl] = __builtin_amdgcn_mfma_f32_16x16x32_bf16(a0, b, acc0[ntl], 0, 0, 0);
            acc1[ntl] = __builtin_amdgcn_mfma_f32_16x16x32_bf16(a1, b, acc1[ntl], 0, 0, 0);
        }
    }
    // epilogue: relu + project onto pq
    float pga[2][4] = {{0,0,0,0},{0,0,0,0}}, pgb[2][4] = {{0,0,0,0},{0,0,0,0}};
    float pua[2][4] = {{0,0,0,0},{0,0,0,0}}, pub[2][4] = {{0,0,0,0},{0,0,0,0}};
#pragma unroll
    for (int ntl = 0; ntl < NTW; ntl++) {
        int col = (wave * NTW + ntl) * 16 + l15;
        float bv = bias[col];
        float wpa = pq[col], wpb = pq[256 + col];
        float wqa = pq[512 + col], wqb = pq[768 + col];
#pragma unroll
        for (int reg = 0; reg < 4; reg++) {
            float v0 = acc0[ntl][reg] + bv;  v0 = v0 > 0.f ? v0 : 0.f;
            float v1 = acc1[ntl][reg] + bv;  v1 = v1 > 0.f ? v1 : 0.f;
            pga[0][reg] += v0 * wpa;  pgb[0][reg] += v0 * wpb;
            pua[0][reg] += v0 * wqa;  pub[0][reg] += v0 * wqb;
            pga[1][reg] += v1 * wpa;  pgb[1][reg] += v1 * wpb;
            pua[1][reg] += v1 * wqa;  pub[1][reg] += v1 * wqb;
        }
    }
#pragma unroll
    for (int off = 1; off < 16; off <<= 1) {
#pragma unroll
        for (int rt = 0; rt < 2; rt++) {
#pragma unroll
            for (int reg = 0; reg < 4; reg++) {
                pga[rt][reg] += __shfl_xor(pga[rt][reg], off, 64);
                pgb[rt][reg] += __shfl_xor(pgb[rt][reg], off, 64);
                pua[rt][reg] += __shfl_xor(pua[rt][reg], off, 64);
                pub[rt][reg] += __shfl_xor(pub[rt][reg], off, 64);
            }
        }
    }
    __shared__ float red[4][4][32];
    if (l15 == 0) {
#pragma unroll
        for (int rt = 0; rt < 2; rt++) {
#pragma unroll
            for (int reg = 0; reg < 4; reg++) {
                int row = rt * 16 + quad * 4 + reg;
                red[0][wave][row] = pga[rt][reg];
                red[1][wave][row] = pgb[rt][reg];
                red[2][wave][row] = pua[rt][reg];
                red[3][wave][row] = pub[rt][reg];
            }
        }
    }
    __syncthreads();
    if (threadIdx.x < 32) {
        int row = threadIdx.x;
        int m = mbase + row;
        if (m < NN) {
            float ga = (red[0][0][row] + red[0][1][row]) + (red[0][2][row] + red[0][3][row]);
            float gb = (red[1][0][row] + red[1][1][row]) + (red[1][2][row] + red[1][3][row]);
            float ua = (red[2][0][row] + red[2][1][row]) + (red[2][2][row] + red[2][3][row]);
            float ub = (red[3][0][row] + red[3][1][row]) + (red[3][2][row] + red[3][3][row]);
            g2[m] = make_float2(ga, gb);
            u2[m] = make_float2(ua, ub);
        }
    }
}

// ---------------- scalar gather-mean + final add: sa/sb per node ----------------------
__global__ void k_sagg(const float2* __restrict__ g2, const float2* __restrict__ u2,
                       const int* __restrict__ rowptr, const int* __restrict__ ssrc,
                       const float* __restrict__ cab,
                       float* __restrict__ sa, float* __restrict__ sb) {
    int n = blockIdx.x * 256 + threadIdx.x;
    if (n >= NN) return;
    int r0 = rowptr[n], r1 = rowptr[n + 1];
    float a0 = 0.f, b0 = 0.f, a1 = 0.f, b1 = 0.f;
    float a2 = 0.f, b2 = 0.f, a3 = 0.f, b3 = 0.f;
    int e = r0;
    for (; e + 4 <= r1; e += 4) {
        float2 v0 = g2[ssrc[e]];
        float2 v1 = g2[ssrc[e + 1]];
        float2 v2 = g2[ssrc[e + 2]];
        float2 v3 = g2[ssrc[e + 3]];
        a0 += v0.x; b0 += v0.y;
        a1 += v1.x; b1 += v1.y;
        a2 += v2.x; b2 += v2.y;
        a3 += v3.x; b3 += v3.y;
    }
    for (; e < r1; e++) {
        float2 v = g2[ssrc[e]];
        a0 += v.x; b0 += v.y;
    }
    float sc = 1.0f / fmaxf((float)(r1 - r0), 1.0f);
    float2 u = u2[n];
    sa[n] = ((a0 + a1) + (a2 + a3)) * sc + u.x + cab[0];
    sb[n] = ((b0 + b1) + (b2 + b3)) * sc + u.y + cab[1];
}

// ---------------- pair scorer: out[p] = sigmoid(sa[a] + sb[b] + blin) ----------------
__global__ void k_pairs(const float* __restrict__ sa, const float* __restrict__ sb,
                        const int* __restrict__ mask, const float* __restrict__ blin,
                        float* __restrict__ out) {
    int p = blockIdx.x * 256 + threadIdx.x;
    if (p >= NP) return;
    int2 m = ((const int2*)mask)[p];
    float v = sa[m.x] + sb[m.y] + blin[0];
    out[p] = 1.0f / (1.0f + __expf(-v));
}

extern "C" void kernel_launch(void* const* d_in, const int* in_sizes, int n_in,
                              void* d_out, int out_size, void* d_ws, size_t ws_size,
                              hipStream_t stream) {
    const float* x    = (const float*)d_in[0];   // [50000,128]
    const int*   ei   = (const int*)  d_in[1];   // [2,600000]
    const int*   mask = (const int*)  d_in[2];   // [200000,2]
    const float* W1l  = (const float*)d_in[3];   // [128,256]
    const float* b1l  = (const float*)d_in[4];   // [256]
    const float* W1r  = (const float*)d_in[5];   // [128,256]
    const float* W2l  = (const float*)d_in[6];   // [256,128]
    const float* b2l  = (const float*)d_in[7];   // [128]
    const float* W2r  = (const float*)d_in[8];   // [256,128]
    const float* Wlin = (const float*)d_in[9];   // [256,1]
    const float* blin = (const float*)d_in[10];  // [1]
    float* out = (float*)d_out;                  // [200000,1]

    const int* src = ei;
    const int* dst = ei + NE;

    char* ws = (char*)d_ws;
    int*    deg    = (int*)(ws);                             // 200 KB
    int*    rowptr = (int*)(ws + (size_t)1 * (1 << 20));
    int*    cursor = (int*)(ws + (size_t)2 * (1 << 20));
    int*    ssrc   = (int*)(ws + (size_t)3 * (1 << 20));     // 2.4 MB
    int*    excl   = (int*)(ws + (size_t)6 * (1 << 20));     // 200 KB
    int*    bsum   = (int*)(ws + (size_t)7 * (1 << 20));     // 196 B
    ushort* Bp1    = (ushort*)(ws + (size_t)8 * (1 << 20));  // 128 KB
    float*  pq     = (float*)(ws + (size_t)9 * (1 << 20));   // 4 KB
    float*  cab    = (float*)(ws + (size_t)9 * (1 << 20) + 65536);
    float*  sa     = (float*)(ws + (size_t)10 * (1 << 20));  // 200 KB
    float*  sb     = (float*)(ws + (size_t)11 * (1 << 20));  // 200 KB
    float2* g2     = (float2*)(ws + (size_t)12 * (1 << 20)); // 400 KB
    float2* u2     = (float2*)(ws + (size_t)13 * (1 << 20)); // 400 KB
    uint*   A1u    = (uint*)(ws + (size_t)14 * (1 << 20));   // [50000,256] bf16 = 25.6 MB

    hipMemsetAsync(deg, 0, (size_t)NN * 4, stream);

    k_pre   <<<(T_CAB + 255) / 256, 256, 0, stream>>>(x, A1u, dst, deg,
                                                      W1l, W1r, Bp1,
                                                      W2l, W2r, Wlin, b2l, pq, cab);
    k_scan1 <<<NB_SCAN, 1024, 0, stream>>>(deg, excl, bsum);
    k_scan23<<<NB_SCAN, 1024, 0, stream>>>(excl, bsum, rowptr, cursor);
    k_fill  <<<(NE + 255) / 256, 256, 0, stream>>>(src, dst, cursor, ssrc);

    k_agg1  <<<NN / 4, 256, 0, stream>>>(A1u, rowptr, ssrc);
    k_gemm1 <<<(NN + 31) / 32, 256, 0, stream>>>((const ushort*)A1u, Bp1, b1l,
                                                 pq, g2, u2);
    k_sagg  <<<(NN + 255) / 256, 256, 0, stream>>>(g2, u2, rowptr, ssrc, cab, sa, sb);
    k_pairs <<<(NP + 255) / 256, 256, 0, stream>>>(sa, sb, mask, blin, out);
}